// Round 18
// baseline (77.695 us; speedup 1.0000x reference)
//
#include <hip/hip_runtime.h>
#include <hip/hip_bf16.h>

// out[n,h,i,j] = logits[i][ clamp(j-i+512, 1, 1023) ],  logits = Q @ R  (per n,h)
// n=4 h=16 L=1024 d=64, table width 1025.
//
// R18: P/C with 3-slot ring, producer runs 2 units AHEAD of consumers.
//   R12's lockstep (produce r | consume r-1, 2 slots) makes consumers eat the
//   producer tail at every barrier (~1.5us/round slop). With 3 slots and
//   producer(r)/consumer(r-2), producer (2.6us busy) never gates consumers
//   (3.3us/round) -> rounds = pure store drain at the nt ceiling.
// Block = (nh, 256 rows) = 16 units x 16 rows; 512 thr = 4P + 4C waves;
// LDS 3 x 33.2 KB = 99.5 KB -> 1 block/CU; grid 256; XCD swizzle; nt stores.
// Producer body = R17 verbatim (16 tiles compile-time, unroll 4).

#define NH 16
#define LQ 1024
#define DD 64
#define TT 1025
#define MAXP 512
#define PADS 4          // left pad in shorts (multiple of 4 keeps 8B alignment)
#define LSTRIDE2 1036   // shorts; row stride 2072 B
#define UNITS 16

typedef float f32x4 __attribute__((ext_vector_type(4)));
typedef short s16x4 __attribute__((ext_vector_type(4)));
typedef short s16x8 __attribute__((ext_vector_type(8)));

__device__ __forceinline__ short f2bf(float f) {
    __hip_bfloat16 h = __float2bfloat16(f);   // RNE
    return __builtin_bit_cast(short, h);
}
__device__ __forceinline__ float bf2f(short s) {
    return __builtin_bit_cast(float, ((unsigned)(unsigned short)s) << 16);
}

// Writer helper: D = wave-uniform misalignment ((512 - i) & 3), compile-time.
template<int D>
__device__ __forceinline__ void write_chunks(const unsigned short* __restrict__ lrow,
                                             float p1, float p2,
                                             int i, int l, float* __restrict__ orow) {
    #pragma unroll
    for (int c = 0; c < 4; ++c) {
        const int j0 = c * 256 + 4 * l;
        const int t0 = j0 - i + MAXP;
        int colA = PADS + t0 - D;                 // = PADS + (t0 & ~3), 8B aligned
        colA = colA < 0 ? 0 : (colA > PADS + LQ ? PADS + LQ : colA);  // clamped lanes: value unused
        s16x4 A = *(const s16x4*)(lrow + colA);
        s16x4 B = {0, 0, 0, 0};
        if (D) B = *(const s16x4*)(lrow + colA + 4);
        f32x4 v;
        #pragma unroll
        for (int e = 0; e < 4; ++e) {
            const int t = t0 + e;
            const float in = bf2f((D + e < 4) ? A[D + e] : B[D + e - 4]);
            v[e] = t < 1 ? p1 : (t > LQ - 1 ? p2 : in);
        }
        __builtin_nontemporal_store(v, (f32x4*)(orow + j0));   // nt (R16: plain is -20us)
    }
}

// grid 256 (1D), block 512 = 8 waves (4 producers + 4 consumers), 16 units/block.
__global__ __launch_bounds__(512, 2) void lpb_pc(const float* __restrict__ Q,
                                                 const float* __restrict__ R,
                                                 float* __restrict__ out) {
    __shared__ unsigned short lg[3][16][LSTRIDE2];   // 3-slot ring, 99.5 KB -> 1 block/CU

    // XCD-chunked bijective swizzle (256 % 8 == 0): XCD k gets nh in [8k, 8k+8)
    const int bidx = blockIdx.x;
    const int swz  = (bidx & 7) * 32 + (bidx >> 3);
    const int nh   = swz >> 2;
    const int rg   = swz & 3;           // 256-row group within (n,h)
    const int h    = nh & (NH - 1);

    const int tid = threadIdx.x;
    const int w = tid >> 6, l = tid & 63;
    const int n = l & 15, g = l >> 4;

    const float* rbase = R + (size_t)(h * DD + 8 * g) * TT;

    #pragma unroll 1
    for (int rnd = 0; rnd < UNITS + 2; ++rnd) {
        if (w < 4) {
            if (rnd < UNITS) {
                // ---- produce unit rnd into slot rnd%3: wave w covers t in [256w, 256w+256)
                const int ibase = rg * 256 + rnd * 16;
                const float* qrow = Q + ((size_t)nh * LQ + (ibase + n)) * DD + 8 * g;
                s16x8 qf[2];    // B-operand: lane (n,g) holds Q[ibase+n][kh*32 + 8g + e]
                #pragma unroll
                for (int kh = 0; kh < 2; ++kh) {
                    f32x4 a = *(const f32x4*)(qrow + kh * 32);
                    f32x4 b = *(const f32x4*)(qrow + kh * 32 + 4);
                    #pragma unroll
                    for (int e = 0; e < 4; ++e) { qf[kh][e] = f2bf(a[e]); qf[kh][4 + e] = f2bf(b[e]); }
                }
                const int slot = rnd % 3;
                unsigned short (*buf)[LSTRIDE2] = lg[slot];
                #pragma unroll 4
                for (int mt = 0; mt < 16; ++mt) {
                    const int tb = w * 256 + mt * 16;
                    const float* rc = rbase + tb + n;
                    s16x8 rf0, rf1;   // A-operand: lane (n,g) holds R[h][8g+e][tb+n]
                    #pragma unroll
                    for (int e = 0; e < 8; ++e) {
                        rf0[e] = f2bf(rc[(size_t)e * TT]);
                        rf1[e] = f2bf(rc[(size_t)(32 + e) * TT]);
                    }
                    f32x4 acc = (f32x4){0.f, 0.f, 0.f, 0.f};
                    acc = __builtin_amdgcn_mfma_f32_16x16x32_bf16(rf0, qf[0], acc, 0, 0, 0);
                    acc = __builtin_amdgcn_mfma_f32_16x16x32_bf16(rf1, qf[1], acc, 0, 0, 0);
                    // D: col=n -> i-local, row=4g+s -> t=tb+4g+s: pack bf16, b64 write
                    s16x4 hv;
                    #pragma unroll
                    for (int s = 0; s < 4; ++s) hv[s] = f2bf(acc[s]);
                    *(s16x4*)&buf[n][PADS + tb + 4 * g] = hv;
                }
            }
        } else {
            if (rnd >= 2) {
                // ---- consume unit rnd-2 from slot (rnd-2)%3: wave (w-4) owns 4 rows
                const int u = rnd - 2;
                const int ibase = rg * 256 + u * 16;
                unsigned short (*buf)[LSTRIDE2] = lg[u % 3];
                const int cw = w - 4;
                #pragma unroll 1
                for (int rr = 0; rr < 4; ++rr) {
                    const int il = cw * 4 + rr;
                    const int i  = ibase + il;
                    const unsigned short* lrow = &buf[il][0];
                    const float p1 = bf2f(lrow[PADS + 1]);          // left clamp constant
                    const float p2 = bf2f(lrow[PADS + LQ - 1]);     // right clamp constant
                    float* orow = out + ((size_t)nh * LQ + i) * LQ;
                    switch ((MAXP - i) & 3) {                       // row-uniform shift
                        case 0: write_chunks<0>(lrow, p1, p2, i, l, orow); break;
                        case 1: write_chunks<1>(lrow, p1, p2, i, l, orow); break;
                        case 2: write_chunks<2>(lrow, p1, p2, i, l, orow); break;
                        default: write_chunks<3>(lrow, p1, p2, i, l, orow); break;
                    }
                }
            }
        }
        __syncthreads();   // producer(rnd) writes slot rnd%3; consumer(rnd) reads (rnd-2)%3;
                           // distinct mod 3 -> producer never gates the store stream
    }
}

extern "C" void kernel_launch(void* const* d_in, const int* in_sizes, int n_in,
                              void* d_out, int out_size, void* d_ws, size_t ws_size,
                              hipStream_t stream) {
    const float* Q = (const float*)d_in[0];
    const float* R = (const float*)d_in[1];
    float* out = (float*)d_out;

    lpb_pc<<<dim3(256), 512, 0, stream>>>(Q, R, out);
}

// Round 19
// 74.330 us; speedup vs baseline: 1.0453x; 1.0453x over previous
//
#include <hip/hip_runtime.h>
#include <hip/hip_bf16.h>

// out[n,h,i,j] = logits[i][ clamp(j-i+512, 1, 1023) ],  logits = Q @ R  (per n,h)
// n=4 h=16 L=1024 d=64, table width 1025.
//
// R19 = R12 verbatim (verified best: 74.0 us) — final revert.
// Producer/consumer wave specialization: block = 4 waves, 2-slot LDS pipeline:
//   round r: waves 0-1 compute unit r (16 i-rows x 1024 t) into lg[r&1];
//            waves 2-3 stream unit r-1 from lg[(r-1)&1] to HBM (nt stores).
// Session A/B ledger: nt>plain (+20us, R16); wave count null (R17); 3-slot
// decoupling null (R18); pret/tile-skip/pre-transpose all regress (R6/R14/R15);
// occupancy/LDS-conflict/R-volume all null (R7/R9/R10). Effective mixed
// read+nt-store rate ~4 TB/s is the structural floor of this decomposition.

#define NH 16
#define LQ 1024
#define DD 64
#define TT 1025
#define MAXP 512
#define PADS 4          // left pad in shorts (multiple of 4 keeps 8B alignment)
#define LSTRIDE2 1036   // shorts; row stride 2072 B
#define UNITS 8

typedef float f32x4 __attribute__((ext_vector_type(4)));
typedef short s16x4 __attribute__((ext_vector_type(4)));
typedef short s16x8 __attribute__((ext_vector_type(8)));

__device__ __forceinline__ short f2bf(float f) {
    __hip_bfloat16 h = __float2bfloat16(f);   // RNE
    return __builtin_bit_cast(short, h);
}
__device__ __forceinline__ float bf2f(short s) {
    return __builtin_bit_cast(float, ((unsigned)(unsigned short)s) << 16);
}

// Writer helper: D = wave-uniform misalignment ((512 - i) & 3), compile-time.
template<int D>
__device__ __forceinline__ void write_chunks(const unsigned short* __restrict__ lrow,
                                             float p1, float p2,
                                             int i, int l, float* __restrict__ orow) {
    #pragma unroll
    for (int c = 0; c < 4; ++c) {
        const int j0 = c * 256 + 4 * l;
        const int t0 = j0 - i + MAXP;
        int colA = PADS + t0 - D;                 // = PADS + (t0 & ~3), 8B aligned
        colA = colA < 0 ? 0 : (colA > PADS + LQ ? PADS + LQ : colA);  // clamped lanes: value unused
        s16x4 A = *(const s16x4*)(lrow + colA);
        s16x4 B = {0, 0, 0, 0};
        if (D) B = *(const s16x4*)(lrow + colA + 4);
        f32x4 v;
        #pragma unroll
        for (int e = 0; e < 4; ++e) {
            const int t = t0 + e;
            const float in = bf2f((D + e < 4) ? A[D + e] : B[D + e - 4]);
            v[e] = t < 1 ? p1 : (t > LQ - 1 ? p2 : in);
        }
        __builtin_nontemporal_store(v, (f32x4*)(orow + j0));   // nt (R16: plain is -20us)
    }
}

// grid 512 (1D), block 256 = 4 waves (2 producers + 2 consumers), 8 units/block.
__global__ __launch_bounds__(256, 2) void lpb_pc(const float* __restrict__ Q,
                                                 const float* __restrict__ R,
                                                 float* __restrict__ out) {
    __shared__ unsigned short lg[2][16][LSTRIDE2];   // 2-slot pipeline, 66.3 KB

    // XCD-chunked bijective swizzle (512 % 8 == 0): XCD k gets nh in [8k, 8k+8)
    const int bidx = blockIdx.x;
    const int swz  = (bidx & 7) * 64 + (bidx >> 3);
    const int nh   = swz >> 3;
    const int ibg  = swz & 7;
    const int h    = nh & (NH - 1);

    const int tid = threadIdx.x;
    const int w = tid >> 6, l = tid & 63;
    const int n = l & 15, g = l >> 4;

    const float* rbase = R + (size_t)(h * DD + 8 * g) * TT;

    #pragma unroll 1
    for (int rnd = 0; rnd <= UNITS; ++rnd) {
        if (w < 2) {
            if (rnd < UNITS) {
                // ---- produce unit rnd into lg[rnd&1]: wave w covers t in [512w, 512w+512)
                const int ibase = (ibg * UNITS + rnd) * 16;
                const float* qrow = Q + ((size_t)nh * LQ + (ibase + n)) * DD + 8 * g;
                s16x8 qf[2];    // B-operand: lane (n,g) holds Q[ibase+n][kh*32 + 8g + e]
                #pragma unroll
                for (int kh = 0; kh < 2; ++kh) {
                    f32x4 a = *(const f32x4*)(qrow + kh * 32);
                    f32x4 b = *(const f32x4*)(qrow + kh * 32 + 4);
                    #pragma unroll
                    for (int e = 0; e < 4; ++e) { qf[kh][e] = f2bf(a[e]); qf[kh][4 + e] = f2bf(b[e]); }
                }
                unsigned short (*buf)[LSTRIDE2] = lg[rnd & 1];
                #pragma unroll 4
                for (int mt = 0; mt < 32; ++mt) {
                    const int tb = w * 512 + mt * 16;
                    const float* rc = rbase + tb + n;
                    s16x8 rf0, rf1;   // A-operand: lane (n,g) holds R[h][8g+e][tb+n]
                    #pragma unroll
                    for (int e = 0; e < 8; ++e) {
                        rf0[e] = f2bf(rc[(size_t)e * TT]);
                        rf1[e] = f2bf(rc[(size_t)(32 + e) * TT]);
                    }
                    f32x4 acc = (f32x4){0.f, 0.f, 0.f, 0.f};
                    acc = __builtin_amdgcn_mfma_f32_16x16x32_bf16(rf0, qf[0], acc, 0, 0, 0);
                    acc = __builtin_amdgcn_mfma_f32_16x16x32_bf16(rf1, qf[1], acc, 0, 0, 0);
                    // D: col=n -> i-local, row=4g+s -> t=tb+4g+s: pack bf16, b64 write
                    s16x4 hv;
                    #pragma unroll
                    for (int s = 0; s < 4; ++s) hv[s] = f2bf(acc[s]);
                    *(s16x4*)&buf[n][PADS + tb + 4 * g] = hv;
                }
            }
        } else {
            if (rnd > 0) {
                // ---- consume unit rnd-1 from lg[(rnd-1)&1]: wave (w-2) owns 8 rows
                const int u = rnd - 1;
                const int ibase = (ibg * UNITS + u) * 16;
                unsigned short (*buf)[LSTRIDE2] = lg[u & 1];
                const int cw = w - 2;
                #pragma unroll 1
                for (int rr = 0; rr < 8; ++rr) {
                    const int il = cw * 8 + rr;
                    const int i  = ibase + il;
                    const unsigned short* lrow = &buf[il][0];
                    const float p1 = bf2f(lrow[PADS + 1]);          // left clamp constant
                    const float p2 = bf2f(lrow[PADS + LQ - 1]);     // right clamp constant
                    float* orow = out + ((size_t)nh * LQ + i) * LQ;
                    switch ((MAXP - i) & 3) {                       // row-uniform shift
                        case 0: write_chunks<0>(lrow, p1, p2, i, l, orow); break;
                        case 1: write_chunks<1>(lrow, p1, p2, i, l, orow); break;
                        case 2: write_chunks<2>(lrow, p1, p2, i, l, orow); break;
                        default: write_chunks<3>(lrow, p1, p2, i, l, orow); break;
                    }
                }
            }
        }
        __syncthreads();   // orders: producer writes(rnd) -> consumer reads(rnd+1);
                           // consumer reads(rnd) -> producer overwrite(rnd+1)
    }
}

extern "C" void kernel_launch(void* const* d_in, const int* in_sizes, int n_in,
                              void* d_out, int out_size, void* d_ws, size_t ws_size,
                              hipStream_t stream) {
    const float* Q = (const float*)d_in[0];
    const float* R = (const float*)d_in[1];
    float* out = (float*)d_out;

    lpb_pc<<<dim3(512), 256, 0, stream>>>(Q, R, out);
}